// Round 1
// baseline (1203.624 us; speedup 1.0000x reference)
//
#include <hip/hip_runtime.h>
#include <cstdint>

// Problem constants
#define KH   4      // n_codebooks (heads)
#define DM   1024   // d_model
#define HID  2048   // hidden
#define RP   1024   // repr
#define VOC  2052   // vocab
#define VPAD 2176   // vocab padded to multiple of 128
#define TT   2048   // T
#define MM   8192   // B*T tokens

typedef short bf16x8 __attribute__((ext_vector_type(8)));
typedef float f32x4  __attribute__((ext_vector_type(4)));

__device__ __forceinline__ unsigned short f2bf(float f) {
  union { float f; unsigned int u; } a; a.f = f;
  unsigned int u = a.u;
  unsigned int r = (u + 0x7fffu + ((u >> 16) & 1u)) >> 16;  // RNE
  return (unsigned short)r;
}

// global -> LDS direct copy, 16B per lane. LDS dst must be wave-uniform base;
// HW writes lane i's 16B to (base + i*16). CK-style addrspace cast pattern.
__device__ __forceinline__ void async_cp16(const unsigned short* g, unsigned short* l) {
  __builtin_amdgcn_global_load_lds(
      (const __attribute__((address_space(1))) unsigned int*)(uintptr_t)g,
      (__attribute__((address_space(3))) unsigned int*)(uintptr_t)l,
      16, 0, 0);
}

// ---------------------------------------------------------------------------
// LayerNorm stats (per token) -> xn bf16 [MM][DM]
// ---------------------------------------------------------------------------
__global__ __launch_bounds__(256) void ln_kernel(const float* __restrict__ x,
                                                 unsigned short* __restrict__ xn) {
  int row = blockIdx.x;
  int tid = threadIdx.x;
  const float4* xr = (const float4*)(x + (size_t)row * DM);
  float4 v = xr[tid];
  float s  = v.x + v.y + v.z + v.w;
  float s2 = v.x * v.x + v.y * v.y + v.z * v.z + v.w * v.w;
  for (int o = 32; o > 0; o >>= 1) {
    s  += __shfl_down(s, o);
    s2 += __shfl_down(s2, o);
  }
  __shared__ float ps[8];
  int wave = tid >> 6, lane = tid & 63;
  if (lane == 0) { ps[wave] = s; ps[wave + 4] = s2; }
  __syncthreads();
  if (tid == 0) {
    float ts  = ps[0] + ps[1] + ps[2] + ps[3];
    float ts2 = ps[4] + ps[5] + ps[6] + ps[7];
    float mean = ts * (1.0f / DM);
    float var  = ts2 * (1.0f / DM) - mean * mean;
    ps[0] = mean;
    ps[1] = rsqrtf(var + 1e-5f);
  }
  __syncthreads();
  float mean = ps[0], rstd = ps[1];
  ushort4 o4;
  o4.x = f2bf((v.x - mean) * rstd);
  o4.y = f2bf((v.y - mean) * rstd);
  o4.z = f2bf((v.z - mean) * rstd);
  o4.w = f2bf((v.w - mean) * rstd);
  ((ushort4*)(xn + (size_t)row * DM))[tid] = o4;
}

// ---------------------------------------------------------------------------
// b1s[k][h] = b1[k][h] + sum_d ln_bias[k][d] * W1[k][d][h]   (fp32)
// grid: (HID/64, KH), block 256 = 64 h-cols x 4 d-chunks
// ---------------------------------------------------------------------------
__global__ __launch_bounds__(256) void fold_b1(const float* __restrict__ W1,
                                               const float* __restrict__ b1,
                                               const float* __restrict__ ln_bias,
                                               float* __restrict__ b1s) {
  int k  = blockIdx.y;
  int h0 = blockIdx.x * 64;
  int hl = threadIdx.x & 63;
  int dg = threadIdx.x >> 6;
  const float* Wk = W1 + (size_t)k * DM * HID;
  const float* lb = ln_bias + (size_t)k * DM;
  float acc = 0.f;
  for (int d = dg * 256; d < dg * 256 + 256; ++d)
    acc += lb[d] * Wk[(size_t)d * HID + h0 + hl];
  __shared__ float red[4][64];
  red[dg][hl] = acc;
  __syncthreads();
  if (dg == 0)
    b1s[(size_t)k * HID + h0 + hl] =
        b1[(size_t)k * HID + h0 + hl] + red[0][hl] + red[1][hl] + red[2][hl] + red[3][hl];
}

// ---------------------------------------------------------------------------
// Transpose + fp32->bf16 convert (+ optional per-src-row scale, for ln_scale*W1)
// src [k][Rr][Cc] fp32  ->  dst [k][Cc(guarded)][Rr] bf16 (head stride dstHeadStride)
// ---------------------------------------------------------------------------
__global__ __launch_bounds__(256) void transpose_conv(const float* __restrict__ src,
                                                      unsigned short* __restrict__ dst,
                                                      const float* __restrict__ scale,
                                                      int Rr, int Cc, int dstHeadStride) {
  int k  = blockIdx.z;
  int c0 = blockIdx.x * 32, r0 = blockIdx.y * 32;
  int tx = threadIdx.x & 31, ty = threadIdx.x >> 5;
  __shared__ float tile[32][33];
  const float* s = src + (size_t)k * Rr * Cc;
  for (int q = 0; q < 4; q++) {
    int r = r0 + ty + q * 8;
    int c = c0 + tx;
    float v = 0.f;
    if (c < Cc) v = s[(size_t)r * Cc + c];
    if (scale) v *= scale[(size_t)k * Rr + r];
    tile[ty + q * 8][tx] = v;
  }
  __syncthreads();
  unsigned short* d = dst + (size_t)k * dstHeadStride;
  for (int q = 0; q < 4; q++) {
    int c = c0 + ty + q * 8;
    int r = r0 + tx;
    if (c < Cc) d[(size_t)c * Rr + r] = f2bf(tile[tx][ty + q * 8]);
  }
}

// ---------------------------------------------------------------------------
// gemm_bt (m97 structure): C[M][N] = A[M][Kd] @ Bt[N][Kd]^T + bias, fused epilogue
// MODE 0: GELU(exact) -> bf16    MODE 1: +bias -> bf16
// MODE 2: +bias -> fp32, strided store into [B,KH,T,V], cols guarded < VOC
// block 256 (4 waves, 2x2 of 64x64), tile 128x128, BK=32
// ---------------------------------------------------------------------------
template <int MODE>
__global__ __launch_bounds__(256) void gemm_bt(const unsigned short* __restrict__ A,
                                               const unsigned short* __restrict__ Bt,
                                               const float* __restrict__ bias,
                                               unsigned short* __restrict__ ob,
                                               float* __restrict__ of,
                                               int Kd, int ldo, int kh) {
  __shared__ __align__(16) unsigned short As[128 * 32];  // [row][k], row stride 32 elem (64B)
  __shared__ __align__(16) unsigned short Bs[128 * 32];  // [n-row][k]

  const int tile_m = blockIdx.y * 128;
  const int tile_n = blockIdx.x * 128;
  const int tid  = threadIdx.x;
  const int wave = tid >> 6;
  const int lane = tid & 63;
  const int wm = (wave & 1) * 64;
  const int wn = (wave >> 1) * 64;

  // Staging: 8KB per tile; wave w covers bytes [w*2048, w*2048+2048) in 2 issues
  const int o0  = wave * 2048 + lane * 16;
  const int o1  = o0 + 1024;
  const int rA0 = o0 >> 6, kA0 = (o0 & 63) >> 1;
  const int rA1 = o1 >> 6, kA1 = (o1 & 63) >> 1;
  const unsigned short* gA0 = A  + (size_t)(tile_m + rA0) * Kd + kA0;
  const unsigned short* gA1 = A  + (size_t)(tile_m + rA1) * Kd + kA1;
  const unsigned short* gB0 = Bt + (size_t)(tile_n + rA0) * Kd + kA0;
  const unsigned short* gB1 = Bt + (size_t)(tile_n + rA1) * Kd + kA1;
  unsigned short* lA0 = As + wave * 1024;        // wave-uniform LDS bases
  unsigned short* lA1 = As + wave * 1024 + 512;
  unsigned short* lB0 = Bs + wave * 1024;
  unsigned short* lB1 = Bs + wave * 1024 + 512;

  f32x4 acc[4][4];
#pragma unroll
  for (int i = 0; i < 4; i++)
#pragma unroll
    for (int j = 0; j < 4; j++) acc[i][j] = (f32x4){0.f, 0.f, 0.f, 0.f};

  const int al = lane & 15;
  const int kq = lane >> 4;  // k-quad: 8-elem group
  const bf16x8* Ap = (const bf16x8*)As;
  const bf16x8* Bp = (const bf16x8*)Bs;

  for (int k0 = 0; k0 < Kd; k0 += 32) {
    async_cp16(gA0 + k0, lA0);
    async_cp16(gA1 + k0, lA1);
    async_cp16(gB0 + k0, lB0);
    async_cp16(gB1 + k0, lB1);
    __syncthreads();  // drains vmcnt (global_load_lds) per gfx950 barrier semantics
    bf16x8 af[4], bf[4];
#pragma unroll
    for (int i = 0; i < 4; i++) af[i] = Ap[(wm + i * 16 + al) * 4 + kq];
#pragma unroll
    for (int j = 0; j < 4; j++) bf[j] = Bp[(wn + j * 16 + al) * 4 + kq];
#pragma unroll
    for (int i = 0; i < 4; i++)
#pragma unroll
      for (int j = 0; j < 4; j++)
        acc[i][j] = __builtin_amdgcn_mfma_f32_16x16x32_bf16(af[i], bf[j], acc[i][j], 0, 0, 0);
    __syncthreads();
  }

  // Epilogue. C/D layout: col = lane&15 (n), row = (lane>>4)*4 + reg (m).
  const int rg = (lane >> 4) * 4;
#pragma unroll
  for (int j = 0; j < 4; j++) {
    int gcol = tile_n + wn + j * 16 + al;
    float bj = 0.f;
    if (MODE != 2 || gcol < VOC) bj = bias[gcol];
#pragma unroll
    for (int i = 0; i < 4; i++) {
      int grow = tile_m + wm + i * 16 + rg;
#pragma unroll
      for (int r = 0; r < 4; r++) {
        float v = acc[i][j][r] + bj;
        if (MODE == 0) {
          v = 0.5f * v * (1.0f + erff(v * 0.70710678118654752f));
          ob[(size_t)(grow + r) * ldo + gcol] = f2bf(v);
        } else if (MODE == 1) {
          ob[(size_t)(grow + r) * ldo + gcol] = f2bf(v);
        } else {
          if (gcol < VOC) {
            int m = grow + r;
            int b = m >> 11, t = m & 2047;  // T = 2048
            of[((size_t)(b * KH + kh) * TT + t) * VOC + gcol] = v;
          }
        }
      }
    }
  }
}

// ---------------------------------------------------------------------------
extern "C" void kernel_launch(void* const* d_in, const int* in_sizes, int n_in,
                              void* d_out, int out_size, void* d_ws, size_t ws_size,
                              hipStream_t stream) {
  const float* x        = (const float*)d_in[0];
  const float* ln_scale = (const float*)d_in[1];
  const float* ln_bias  = (const float*)d_in[2];
  const float* W1       = (const float*)d_in[3];
  const float* b1       = (const float*)d_in[4];
  const float* W2       = (const float*)d_in[5];
  const float* b2       = (const float*)d_in[6];
  const float* Wc       = (const float*)d_in[7];
  const float* bc       = (const float*)d_in[8];
  float* out = (float*)d_out;

  // workspace carve-up (~113 MB total)
  char* p = (char*)d_ws;
  auto alloc = [&](size_t bytes) {
    char* r = p;
    p += (bytes + 255) & ~(size_t)255;
    return r;
  };
  unsigned short* xn   = (unsigned short*)alloc((size_t)MM * DM * 2);
  unsigned short* w1t  = (unsigned short*)alloc((size_t)KH * HID * DM * 2);   // [k][h][d]
  float*          b1s  = (float*)alloc((size_t)KH * HID * 4);
  unsigned short* w2t  = (unsigned short*)alloc((size_t)KH * RP * HID * 2);   // [k][r][h]
  unsigned short* wct  = (unsigned short*)alloc((size_t)KH * VPAD * RP * 2);  // [k][v][r]
  unsigned short* hbuf = (unsigned short*)alloc((size_t)MM * HID * 2);        // per-head reuse
  unsigned short* gbuf = (unsigned short*)alloc((size_t)MM * RP * 2);         // per-head reuse

  ln_kernel<<<MM, 256, 0, stream>>>(x, xn);
  fold_b1<<<dim3(HID / 64, KH), 256, 0, stream>>>(W1, b1, ln_bias, b1s);
  transpose_conv<<<dim3(HID / 32, DM / 32, KH), 256, 0, stream>>>(W1, w1t, ln_scale, DM, HID, HID * DM);
  transpose_conv<<<dim3(RP / 32, HID / 32, KH), 256, 0, stream>>>(W2, w2t, nullptr, HID, RP, RP * HID);
  transpose_conv<<<dim3((VOC + 31) / 32, RP / 32, KH), 256, 0, stream>>>(Wc, wct, nullptr, RP, VOC, VPAD * RP);

  for (int kh = 0; kh < KH; kh++) {
    gemm_bt<0><<<dim3(HID / 128, MM / 128), 256, 0, stream>>>(
        xn, w1t + (size_t)kh * HID * DM, b1s + (size_t)kh * HID, hbuf, nullptr, DM, HID, kh);
    gemm_bt<1><<<dim3(RP / 128, MM / 128), 256, 0, stream>>>(
        hbuf, w2t + (size_t)kh * RP * HID, b2 + (size_t)kh * RP, gbuf, nullptr, HID, RP, kh);
    gemm_bt<2><<<dim3(VPAD / 128, MM / 128), 256, 0, stream>>>(
        gbuf, wct + (size_t)kh * VPAD * RP, bc + (size_t)kh * VOC, nullptr, out, RP, 0, kh);
  }
}

// Round 2
// 1050.415 us; speedup vs baseline: 1.1459x; 1.1459x over previous
//
#include <hip/hip_runtime.h>
#include <cstdint>

// Problem constants
#define KH   4      // n_codebooks (heads)
#define DM   1024   // d_model
#define HID  2048   // hidden
#define RP   1024   // repr
#define VOC  2052   // vocab
#define VPAD 2176   // vocab padded to multiple of 128
#define TT   2048   // T
#define MM   8192   // B*T tokens

typedef short bf16x8 __attribute__((ext_vector_type(8)));
typedef float f32x4  __attribute__((ext_vector_type(4)));

__device__ __forceinline__ unsigned short f2bf(float f) {
  union { float f; unsigned int u; } a; a.f = f;
  unsigned int u = a.u;
  unsigned int r = (u + 0x7fffu + ((u >> 16) & 1u)) >> 16;  // RNE
  return (unsigned short)r;
}

// Fast exact-ish GELU: tanh form via hw exp+rcp. |err vs erf-GELU| < ~5e-4,
// below bf16 quantization of the output. gelu(v) = v * (1 - 1/(exp(2u)+1)),
// u = sqrt(2/pi) * (v + 0.044715 v^3).
__device__ __forceinline__ float fast_gelu(float v) {
  float u = v * (0.7978845608028654f + 0.035677408136300125f * v * v);
  float e = __expf(2.0f * u);                 // overflow -> inf is fine
  float r = __builtin_amdgcn_rcpf(e + 1.0f);  // inf -> 0
  return v - v * r;
}

// global -> LDS direct copy, 16B per lane. LDS dst must be wave-uniform base;
// HW writes lane i's 16B to (base + i*16).
__device__ __forceinline__ void async_cp16(const unsigned short* g, unsigned short* l) {
  __builtin_amdgcn_global_load_lds(
      (const __attribute__((address_space(1))) unsigned int*)(uintptr_t)g,
      (__attribute__((address_space(3))) unsigned int*)(uintptr_t)l,
      16, 0, 0);
}

// ---------------------------------------------------------------------------
// LayerNorm stats (per token) -> xn bf16 [MM][DM]
// ---------------------------------------------------------------------------
__global__ __launch_bounds__(256) void ln_kernel(const float* __restrict__ x,
                                                 unsigned short* __restrict__ xn) {
  int row = blockIdx.x;
  int tid = threadIdx.x;
  const float4* xr = (const float4*)(x + (size_t)row * DM);
  float4 v = xr[tid];
  float s  = v.x + v.y + v.z + v.w;
  float s2 = v.x * v.x + v.y * v.y + v.z * v.z + v.w * v.w;
  for (int o = 32; o > 0; o >>= 1) {
    s  += __shfl_down(s, o);
    s2 += __shfl_down(s2, o);
  }
  __shared__ float ps[8];
  int wave = tid >> 6, lane = tid & 63;
  if (lane == 0) { ps[wave] = s; ps[wave + 4] = s2; }
  __syncthreads();
  if (tid == 0) {
    float ts  = ps[0] + ps[1] + ps[2] + ps[3];
    float ts2 = ps[4] + ps[5] + ps[6] + ps[7];
    float mean = ts * (1.0f / DM);
    float var  = ts2 * (1.0f / DM) - mean * mean;
    ps[0] = mean;
    ps[1] = rsqrtf(var + 1e-5f);
  }
  __syncthreads();
  float mean = ps[0], rstd = ps[1];
  ushort4 o4;
  o4.x = f2bf((v.x - mean) * rstd);
  o4.y = f2bf((v.y - mean) * rstd);
  o4.z = f2bf((v.z - mean) * rstd);
  o4.w = f2bf((v.w - mean) * rstd);
  ((ushort4*)(xn + (size_t)row * DM))[tid] = o4;
}

// ---------------------------------------------------------------------------
// b1s[k][h] = b1[k][h] + sum_d ln_bias[k][d] * W1[k][d][h]   (fp32)
// ---------------------------------------------------------------------------
__global__ __launch_bounds__(256) void fold_b1(const float* __restrict__ W1,
                                               const float* __restrict__ b1,
                                               const float* __restrict__ ln_bias,
                                               float* __restrict__ b1s) {
  int k  = blockIdx.y;
  int h0 = blockIdx.x * 64;
  int hl = threadIdx.x & 63;
  int dg = threadIdx.x >> 6;
  const float* Wk = W1 + (size_t)k * DM * HID;
  const float* lb = ln_bias + (size_t)k * DM;
  float acc = 0.f;
  for (int d = dg * 256; d < dg * 256 + 256; ++d)
    acc += lb[d] * Wk[(size_t)d * HID + h0 + hl];
  __shared__ float red[4][64];
  red[dg][hl] = acc;
  __syncthreads();
  if (dg == 0)
    b1s[(size_t)k * HID + h0 + hl] =
        b1[(size_t)k * HID + h0 + hl] + red[0][hl] + red[1][hl] + red[2][hl] + red[3][hl];
}

// ---------------------------------------------------------------------------
// Transpose + fp32->bf16 convert (+ optional per-src-row scale)
// src [k][Rr][Cc] fp32  ->  dst [k][Cc(guarded)][Rr] bf16
// ---------------------------------------------------------------------------
__global__ __launch_bounds__(256) void transpose_conv(const float* __restrict__ src,
                                                      unsigned short* __restrict__ dst,
                                                      const float* __restrict__ scale,
                                                      int Rr, int Cc, int dstHeadStride) {
  int k  = blockIdx.z;
  int c0 = blockIdx.x * 32, r0 = blockIdx.y * 32;
  int tx = threadIdx.x & 31, ty = threadIdx.x >> 5;
  __shared__ float tile[32][33];
  const float* s = src + (size_t)k * Rr * Cc;
  for (int q = 0; q < 4; q++) {
    int r = r0 + ty + q * 8;
    int c = c0 + tx;
    float v = 0.f;
    if (c < Cc) v = s[(size_t)r * Cc + c];
    if (scale) v *= scale[(size_t)k * Rr + r];
    tile[ty + q * 8][tx] = v;
  }
  __syncthreads();
  unsigned short* d = dst + (size_t)k * dstHeadStride;
  for (int q = 0; q < 4; q++) {
    int c = c0 + ty + q * 8;
    int r = r0 + tx;
    if (c < Cc) d[(size_t)c * Rr + r] = f2bf(tile[tx][ty + q * 8]);
  }
}

// ---------------------------------------------------------------------------
// Grouped gemm_bt (m97 structure): per head kh = blockIdx.z + khBase,
// C[M][N] = A[M][Kd] @ Bt[N][Kd]^T + bias, fused epilogue.
// MODE 0: GELU -> bf16    MODE 1: +bias -> bf16
// MODE 2: +bias -> fp32, strided store into [B,KH,T,V], cols guarded < VOC
// block 256 (4 waves, 2x2 of 64x64), tile 128x128, BK=32
// ---------------------------------------------------------------------------
template <int MODE>
__global__ __launch_bounds__(256) void gemm_bt(const unsigned short* __restrict__ A,
                                               size_t aStrideH,
                                               const unsigned short* __restrict__ Bt,
                                               size_t bStrideH,
                                               const float* __restrict__ bias,
                                               int biasStrideH,
                                               unsigned short* __restrict__ ob,
                                               size_t obStrideH,
                                               float* __restrict__ of,
                                               int Kd, int ldo, int khBase) {
  __shared__ __align__(16) unsigned short As[128 * 32];  // [row][k], 64B/row
  __shared__ __align__(16) unsigned short Bs[128 * 32];

  const int kh = blockIdx.z + khBase;
  A    += (size_t)kh * aStrideH;
  Bt   += (size_t)kh * bStrideH;
  bias += (size_t)kh * biasStrideH;
  ob   += (size_t)kh * obStrideH;

  const int tile_m = blockIdx.y * 128;
  const int tile_n = blockIdx.x * 128;
  const int tid  = threadIdx.x;
  const int wave = tid >> 6;
  const int lane = tid & 63;
  const int wm = (wave & 1) * 64;
  const int wn = (wave >> 1) * 64;

  // Staging: 8KB per tile; wave w covers bytes [w*2048, w*2048+2048) in 2 issues
  const int o0  = wave * 2048 + lane * 16;
  const int o1  = o0 + 1024;
  const int rA0 = o0 >> 6, kA0 = (o0 & 63) >> 1;
  const int rA1 = o1 >> 6, kA1 = (o1 & 63) >> 1;
  const unsigned short* gA0 = A  + (size_t)(tile_m + rA0) * Kd + kA0;
  const unsigned short* gA1 = A  + (size_t)(tile_m + rA1) * Kd + kA1;
  const unsigned short* gB0 = Bt + (size_t)(tile_n + rA0) * Kd + kA0;
  const unsigned short* gB1 = Bt + (size_t)(tile_n + rA1) * Kd + kA1;
  unsigned short* lA0 = As + wave * 1024;  // wave-uniform LDS bases
  unsigned short* lA1 = As + wave * 1024 + 512;
  unsigned short* lB0 = Bs + wave * 1024;
  unsigned short* lB1 = Bs + wave * 1024 + 512;

  f32x4 acc[4][4];
#pragma unroll
  for (int i = 0; i < 4; i++)
#pragma unroll
    for (int j = 0; j < 4; j++) acc[i][j] = (f32x4){0.f, 0.f, 0.f, 0.f};

  const int al = lane & 15;
  const int kq = lane >> 4;
  const bf16x8* Ap = (const bf16x8*)As;
  const bf16x8* Bp = (const bf16x8*)Bs;

  for (int k0 = 0; k0 < Kd; k0 += 32) {
    async_cp16(gA0 + k0, lA0);
    async_cp16(gA1 + k0, lA1);
    async_cp16(gB0 + k0, lB0);
    async_cp16(gB1 + k0, lB1);
    __syncthreads();
    bf16x8 af[4], bf[4];
#pragma unroll
    for (int i = 0; i < 4; i++) af[i] = Ap[(wm + i * 16 + al) * 4 + kq];
#pragma unroll
    for (int j = 0; j < 4; j++) bf[j] = Bp[(wn + j * 16 + al) * 4 + kq];
#pragma unroll
    for (int i = 0; i < 4; i++)
#pragma unroll
      for (int j = 0; j < 4; j++)
        acc[i][j] = __builtin_amdgcn_mfma_f32_16x16x32_bf16(af[i], bf[j], acc[i][j], 0, 0, 0);
    __syncthreads();
  }

  // Epilogue. C/D layout: col = lane&15 (n), row = (lane>>4)*4 + reg (m).
  const int rg = (lane >> 4) * 4;
#pragma unroll
  for (int j = 0; j < 4; j++) {
    int gcol = tile_n + wn + j * 16 + al;
    float bj = 0.f;
    if (MODE != 2 || gcol < VOC) bj = bias[gcol];
#pragma unroll
    for (int i = 0; i < 4; i++) {
      int grow = tile_m + wm + i * 16 + rg;
#pragma unroll
      for (int r = 0; r < 4; r++) {
        float v = acc[i][j][r] + bj;
        if (MODE == 0) {
          ob[(size_t)(grow + r) * ldo + gcol] = f2bf(fast_gelu(v));
        } else if (MODE == 1) {
          ob[(size_t)(grow + r) * ldo + gcol] = f2bf(v);
        } else {
          if (gcol < VOC) {
            int m = grow + r;
            int b = m >> 11, t = m & 2047;  // T = 2048
            of[((size_t)(b * KH + kh) * TT + t) * VOC + gcol] = v;
          }
        }
      }
    }
  }
}

// ---------------------------------------------------------------------------
extern "C" void kernel_launch(void* const* d_in, const int* in_sizes, int n_in,
                              void* d_out, int out_size, void* d_ws, size_t ws_size,
                              hipStream_t stream) {
  const float* x        = (const float*)d_in[0];
  const float* ln_scale = (const float*)d_in[1];
  const float* ln_bias  = (const float*)d_in[2];
  const float* W1       = (const float*)d_in[3];
  const float* b1       = (const float*)d_in[4];
  const float* W2       = (const float*)d_in[5];
  const float* b2       = (const float*)d_in[6];
  const float* Wc       = (const float*)d_in[7];
  const float* bc       = (const float*)d_in[8];
  float* out = (float*)d_out;

  char* p = (char*)d_ws;
  auto alloc = [&](size_t bytes) {
    char* r = p;
    p += (bytes + 255) & ~(size_t)255;
    return r;
  };
  unsigned short* xn  = (unsigned short*)alloc((size_t)MM * DM * 2);
  unsigned short* w1t = (unsigned short*)alloc((size_t)KH * HID * DM * 2);   // [k][h][d]
  float*          b1s = (float*)alloc((size_t)KH * HID * 4);
  unsigned short* w2t = (unsigned short*)alloc((size_t)KH * RP * HID * 2);   // [k][r][h]
  unsigned short* wct = (unsigned short*)alloc((size_t)KH * VPAD * RP * 2);  // [k][v][r]

  // Batched path needs per-head activation buffers; fall back if ws is small.
  const size_t fixed = (size_t)(p - (char*)d_ws);
  const size_t needBatched = fixed + ((size_t)KH * MM * HID * 2 + 256) + ((size_t)KH * MM * RP * 2 + 256);
  const bool batched = ws_size >= needBatched;

  unsigned short* hbuf;
  unsigned short* gbuf;
  size_t hStride, gStride;
  if (batched) {
    hbuf = (unsigned short*)alloc((size_t)KH * MM * HID * 2);
    gbuf = (unsigned short*)alloc((size_t)KH * MM * RP * 2);
    hStride = (size_t)MM * HID;
    gStride = (size_t)MM * RP;
  } else {
    hbuf = (unsigned short*)alloc((size_t)MM * HID * 2);
    gbuf = (unsigned short*)alloc((size_t)MM * RP * 2);
    hStride = 0;
    gStride = 0;
  }

  ln_kernel<<<MM, 256, 0, stream>>>(x, xn);
  fold_b1<<<dim3(HID / 64, KH), 256, 0, stream>>>(W1, b1, ln_bias, b1s);
  transpose_conv<<<dim3(HID / 32, DM / 32, KH), 256, 0, stream>>>(W1, w1t, ln_scale, DM, HID, HID * DM);
  transpose_conv<<<dim3(RP / 32, HID / 32, KH), 256, 0, stream>>>(W2, w2t, nullptr, HID, RP, RP * HID);
  transpose_conv<<<dim3((VOC + 31) / 32, RP / 32, KH), 256, 0, stream>>>(Wc, wct, nullptr, RP, VOC, VPAD * RP);

  if (batched) {
    gemm_bt<0><<<dim3(HID / 128, MM / 128, KH), 256, 0, stream>>>(
        xn, 0, w1t, (size_t)HID * DM, b1s, HID, hbuf, hStride, nullptr, DM, HID, 0);
    gemm_bt<1><<<dim3(RP / 128, MM / 128, KH), 256, 0, stream>>>(
        hbuf, hStride, w2t, (size_t)RP * HID, b2, RP, gbuf, gStride, nullptr, HID, RP, 0);
    gemm_bt<2><<<dim3(VPAD / 128, MM / 128, KH), 256, 0, stream>>>(
        gbuf, gStride, wct, (size_t)VPAD * RP, bc, VOC, nullptr, 0, out, RP, 0, 0);
  } else {
    for (int kh = 0; kh < KH; kh++) {
      gemm_bt<0><<<dim3(HID / 128, MM / 128, 1), 256, 0, stream>>>(
          xn, 0, w1t + (size_t)kh * HID * DM, 0, b1s + (size_t)kh * HID, 0,
          hbuf, 0, nullptr, DM, HID, kh);
      gemm_bt<1><<<dim3(RP / 128, MM / 128, 1), 256, 0, stream>>>(
          hbuf, 0, w2t + (size_t)kh * RP * HID, 0, b2 + (size_t)kh * RP, 0,
          gbuf, 0, nullptr, HID, RP, kh);
      gemm_bt<2><<<dim3(VPAD / 128, MM / 128, 1), 256, 0, stream>>>(
          gbuf, 0, wct + (size_t)kh * VPAD * RP, 0, bc + (size_t)kh * VOC, 0,
          nullptr, 0, out, RP, 0, kh);
    }
  }
}